// Round 3
// baseline (515.099 us; speedup 1.0000x reference)
//
#include <hip/hip_runtime.h>

// VarianceAdaptor: B=16, S=512, C(D_MODEL)=F(FILTER)=512, K=3, T(MAX_FRAMES)=2048
#define B_ 16
#define S_ 512
#define C_ 512
#define T_ 2048

typedef __attribute__((ext_vector_type(8))) short short8;
typedef __attribute__((ext_vector_type(4))) float floatx4;

__device__ __forceinline__ unsigned short f2bf(float x) {
    union { float f; unsigned u; } c; c.f = x;
    unsigned r = (c.u + 0x7fffu + ((c.u >> 16) & 1u)) >> 16;
    return (unsigned short)r;
}

// async global->LDS, 16B per lane; lds dest = wave-uniform base + lane*16
__device__ __forceinline__ void gld_lds16(void* l, const void* g) {
    __builtin_amdgcn_global_load_lds(
        (const __attribute__((address_space(1))) void*)g,
        (__attribute__((address_space(3))) void*)l, 16, 0, 0);
}

// ---------------------------------------------------------------------------
// Fused prep (unchanged): pack 6 conv weights (F,C,3)fp32 -> (3,F,C)bf16,
// cast H->bf16, zero zrow, length-regulator rowidx, fill preds w/ final bias.
__global__ void prep_kernel(const float* __restrict__ w0, const float* __restrict__ w1,
                            const float* __restrict__ w2, const float* __restrict__ w3,
                            const float* __restrict__ w4, const float* __restrict__ w5,
                            unsigned short* __restrict__ wpack,
                            const float* __restrict__ H, unsigned short* __restrict__ Hbf,
                            unsigned short* __restrict__ zrow,
                            const int* __restrict__ Dgt, int* __restrict__ ridx,
                            float* __restrict__ Dp, float* __restrict__ Pp, float* __restrict__ Ep,
                            const float* __restrict__ dbl, const float* __restrict__ pbl,
                            const float* __restrict__ ebl) {
    __shared__ int cs[S_];
    __shared__ int ps[256];
    int blk = blockIdx.x;
    int tid = threadIdx.x;
    if (blk < 6144) {                      // weight pack: 6 x 1024 blocks
        int which = blk >> 10;
        const float* w = which == 0 ? w0 : which == 1 ? w1 : which == 2 ? w2
                       : which == 3 ? w3 : which == 4 ? w4 : w5;
        unsigned short* wp = wpack + (long)which * 786432;
        int i = (blk & 1023) * 256 + tid;   // i over F*C = 262144
        const float* s = w + (long)i * 3;
        wp[i]          = f2bf(s[0]);
        wp[i + 262144] = f2bf(s[1]);
        wp[i + 524288] = f2bf(s[2]);
    } else if (blk < 10240) {              // H fp32 -> bf16: 4096 blocks x 4 elems
        int i = (blk - 6144) * 256 + tid;
        float4 v = *(const float4*)(H + (long)i * 4);
        ushort4 o;
        o.x = f2bf(v.x); o.y = f2bf(v.y); o.z = f2bf(v.z); o.w = f2bf(v.w);
        *(ushort4*)(Hbf + (long)i * 4) = o;
    } else if (blk < 10242) {              // zrow: 2 blocks
        zrow[(blk - 10240) * 256 + tid] = 0;
    } else if (blk < 10258) {              // expand rowidx: 16 blocks (one/batch)
        int b = blk - 10242;
        int t2 = tid * 2;
        int d0 = Dgt[b * S_ + t2], d1 = Dgt[b * S_ + t2 + 1];
        int a0 = d0 < 0 ? 0 : d0, a1 = d1 < 0 ? 0 : d1;
        ps[tid] = a0 + a1;
        __syncthreads();
        for (int off = 1; off < 256; off <<= 1) {
            int v = (tid >= off) ? ps[tid - off] : 0;
            __syncthreads();
            ps[tid] += v;
            __syncthreads();
        }
        int incl = ps[tid];
        cs[t2] = incl - a1;
        cs[t2 + 1] = incl;
        __syncthreads();
        int total = cs[S_ - 1];
        int limit = total < T_ ? total : T_;
        for (int t = tid; t < T_; t += 256) {
            int lo = 0, hi = S_;
            while (lo < hi) { int mid = (lo + hi) >> 1; if (cs[mid] <= t) lo = mid + 1; else hi = mid; }
            if (lo > S_ - 1) lo = S_ - 1;
            ridx[b * T_ + t] = (t < limit) ? lo : -1;
        }
    } else {                               // fill preds: 288 blocks
        int i = (blk - 10258) * 256 + tid;
        if (i < 8192) Dp[i] = dbl[0];
        else if (i < 40960) Pp[i - 8192] = pbl[0];
        else Ep[i - 40960] = ebl[0];
    }
}

// ---------------------------------------------------------------------------
// 256x256-tile 8-wave conv-GEMM with phase barriers + counted vmcnt.
//   D[f, p] = sum_{tap, c} W[tap][f][c] * X[row(p + tap - 1)][c]
// K-tiles ordered c-block-major (cc=0..7, 64 c each), tap-minor (0..2); X is
// staged once per cc (double-buffered per cc parity), W per K-tile (parity
// (cc+tap)&1). Per wave: 128(f) x 64(p) output = acc[8][4]; per K-tile 4
// phases x 16 MFMA; B(X)-frags held in regs across phases (0.375KB LDS/MFMA).
// LDS layout per tile buffer: rows of 64 shorts (128B = 8 x 16B chunks);
// 16B chunk c8 of row r holds global chunk c8 ^ (r&7)  (bank swizzle; reads
// land 2-way max = free). Staging: linear LDS dest, inverse-swizzled source.
struct ConvJob {
    const unsigned short* X;    // bf16 rows [B << Bshift][C]
    const int* ridx;            // per (b,t) row-in-batch, or nullptr = identity
    int Lshift;                 // log2 positions per batch
    int Bshift;                 // log2 rows per batch of X
    const unsigned short* wp;   // [3][512][512] bf16
    const float* bias;
    const float* wl;
    void* dst;
    int nxshift;                // log2 of position tiles (BN=256)
};

template <int TAP, typename F0, typename F1, typename F2, typename F3>
__device__ __forceinline__ void kt_body(
    floatx4 (&acc)[8][4],
    const unsigned short* __restrict__ Wb_, const unsigned short* __restrict__ Xb_,
    int wm, int wn, int q, int lr, F0 s0, F1 s1, F2 s2, F3 s3)
{
    // B (X) fragments: rows wn*64 + jj*16 + lr + TAP, chunks (k*4+q)^(row&7)
    short8 bfr[4][2];
#pragma unroll
    for (int jj = 0; jj < 4; ++jj) {
        const int xr = wn * 64 + jj * 16 + lr + TAP;
        const unsigned short* xp = Xb_ + xr * 64;
        const int sX = xr & 7;
        bfr[jj][0] = *(const short8*)(xp + ((q ^ sX) * 8));
        bfr[jj][1] = *(const short8*)(xp + (((4 + q) ^ sX) * 8));
    }
#pragma unroll
    for (int ph = 0; ph < 4; ++ph) {
        const int wr = wm * 128 + ph * 32 + lr;
        const unsigned short* ap0 = Wb_ + wr * 64;
        const unsigned short* ap1 = ap0 + 1024;         // +16 rows
        const int sA = lr & 7;
        short8 a00 = *(const short8*)(ap0 + ((q ^ sA) * 8));
        short8 a01 = *(const short8*)(ap0 + (((4 + q) ^ sA) * 8));
        short8 a10 = *(const short8*)(ap1 + ((q ^ sA) * 8));
        short8 a11 = *(const short8*)(ap1 + (((4 + q) ^ sA) * 8));
        if (ph == 0) s0(); else if (ph == 1) s1(); else if (ph == 2) s2(); else s3();
        __builtin_amdgcn_s_setprio(1);
#pragma unroll
        for (int jj = 0; jj < 4; ++jj) {
            acc[ph*2][jj]   = __builtin_amdgcn_mfma_f32_16x16x32_bf16(a00, bfr[jj][0], acc[ph*2][jj],   0, 0, 0);
            acc[ph*2][jj]   = __builtin_amdgcn_mfma_f32_16x16x32_bf16(a01, bfr[jj][1], acc[ph*2][jj],   0, 0, 0);
            acc[ph*2+1][jj] = __builtin_amdgcn_mfma_f32_16x16x32_bf16(a10, bfr[jj][0], acc[ph*2+1][jj], 0, 0, 0);
            acc[ph*2+1][jj] = __builtin_amdgcn_mfma_f32_16x16x32_bf16(a11, bfr[jj][1], acc[ph*2+1][jj], 0, 0, 0);
        }
        __builtin_amdgcn_s_setprio(0);
        __builtin_amdgcn_s_barrier();
    }
}

// counted wait + publish barrier (wait BEFORE barrier so all waves' loads done)
#define VMWAIT(n) do { \
    asm volatile("s_waitcnt vmcnt(" #n ")" ::: "memory"); \
    __builtin_amdgcn_sched_barrier(0); \
    __builtin_amdgcn_s_barrier(); \
    __builtin_amdgcn_sched_barrier(0); \
} while (0)

__global__ __launch_bounds__(512, 2) void mega_kernel(
    ConvJob j0, ConvJob j1, ConvJob j2, int e0, int e1, int e2, int mode, int aoff,
    const unsigned short* __restrict__ zrow,
    const float* __restrict__ H, const int* __restrict__ aridx,
    const float* __restrict__ Pgt, const float* __restrict__ Egt,
    const float* __restrict__ pw, const float* __restrict__ pb,
    const float* __restrict__ ew, const float* __restrict__ eb,
    float* __restrict__ aout)
{
    extern __shared__ unsigned short lds[];   // 131584 B: W[2][16384] + X[2][16512] shorts
    const int bx = blockIdx.x;
    const int tid = threadIdx.x;

    if (bx >= e2) {
        // ---- adapt path: 512-thread blocks, aoff selects half ----
        int ab = bx - e2 + aoff;
#pragma unroll
        for (int it = 0; it < 8; ++it) {
            int i = ab * 512 + tid + it * 524288;
            int f4 = i & 127;
            int p  = i >> 7;
            int b  = p >> 11;
            int r  = aridx[p];
            float pg = Pgt[p], eg = Egt[p];
            int f = f4 << 2;
            float4 pwv = *(const float4*)(pw + f);
            float4 pbv = *(const float4*)(pb + f);
            float4 ewv = *(const float4*)(ew + f);
            float4 ebv = *(const float4*)(eb + f);
            float4 h = make_float4(0.f, 0.f, 0.f, 0.f);
            if (r >= 0) h = *(const float4*)(H + ((long)b * S_ + r) * C_ + f);
            float4 o;
            o.x = h.x + pg * pwv.x + pbv.x + eg * ewv.x + ebv.x;
            o.y = h.y + pg * pwv.y + pbv.y + eg * ewv.y + ebv.y;
            o.z = h.z + pg * pwv.z + pbv.z + eg * ewv.z + ebv.z;
            o.w = h.w + pg * pwv.w + pbv.w + eg * ewv.w + ebv.w;
            *(float4*)(aout + (long)p * C_ + f) = o;
        }
        return;
    }

    ConvJob j;
    int local;
    if (bx < e0)      { j = j0; local = bx; }
    else if (bx < e1) { j = j1; local = bx - e0; }
    else              { j = j2; local = bx - e1; }
    const int m0 = (local >> j.nxshift) * 256;
    const int n0 = (local & ((1 << j.nxshift) - 1)) * 256;
    const int L = 1 << j.Lshift;
    const int b = n0 >> j.Lshift;
    const int t0 = n0 & (L - 1);

    unsigned short* WtS = lds;            // [2][16384]
    unsigned short* XtS = lds + 32768;    // [2][16512]  (258 rows x 64)
    char* WtB = (char*)WtS;
    char* XtB = (char*)XtS;

    const int w = tid >> 6, l = tid & 63;
    const int q = l >> 4, lr = l & 15;
    const int wm = w & 1, wn = w >> 1;

    floatx4 acc[8][4];
#pragma unroll
    for (int i = 0; i < 8; ++i)
#pragma unroll
        for (int jj = 0; jj < 4; ++jj) acc[i][jj] = (floatx4){0.f, 0.f, 0.f, 0.f};

    // ---- staging source pointers (16B chunks, inverse-swizzled source) ----
    // instr qq stages chunk ch = qq*512 + w*64 + l: row = ch>>3, c8 = l&7.
    const int swz = ((l & 7) ^ ((l >> 3) & 7)) * 8;
    auto xrowp = [&](int r) -> const unsigned short* {
        int t = t0 - 1 + r;
        if (t < 0 || t >= L) return zrow;
        int rr = j.ridx ? j.ridx[(b << j.Lshift) + t] : t;
        if (rr < 0) return zrow;
        return j.X + ((long)(b << j.Bshift) + rr) * C_;
    };
    const unsigned short* wsrc[4];
    const unsigned short* xsrc[4];
#pragma unroll
    for (int qq = 0; qq < 4; ++qq) {
        int row = qq * 64 + w * 8 + (l >> 3);
        wsrc[qq] = j.wp + (long)(m0 + row) * C_ + swz;
        xsrc[qq] = xrowp(row) + swz;
    }
    // extra X rows 256,257: chunks ch_e = w*2 + lane(0,1)
    const int ch_e = w * 2 + (l & 1);
    const int row_e = 256 + (ch_e >> 3);
    const unsigned short* xsrcE = xrowp(row_e) + (((ch_e & 7) ^ (row_e & 7)) * 8);

    auto issueW = [&](int buf, int qq, int koff) {
        gld_lds16(WtB + buf * 32768 + qq * 8192 + w * 1024, wsrc[qq] + koff);
    };
    auto issueX = [&](int buf, int qq, int xoff) {
        gld_lds16(XtB + buf * 33024 + qq * 8192 + w * 1024, xsrc[qq] + xoff);
    };
    auto issueXe = [&](int buf, int xoff) {
        if (l < 2) gld_lds16(XtB + buf * 33024 + 32768 + w * 32, xsrcE + xoff);
    };

    // ---- prologue: X(cc=0) [5 ops] + W(kt=0: tap0,cc0) [4 ops] ----
    issueX(0, 0, 0); issueX(0, 1, 0); issueX(0, 2, 0); issueX(0, 3, 0); issueXe(0, 0);
    issueW(0, 0, 0); issueW(0, 1, 0); issueW(0, 2, 0); issueW(0, 3, 0);

    // ---- main loop: cc-major, tap-minor; W parity (cc+tap)&1, X parity cc&1.
    // In-flight accounting (steady): tap0 wait drains X(cc)[5]+W(tap0)[4] -> vmcnt(0)
    // (all issued >= 1 K-tile earlier); tap1 wait drains W(tap1)[4] -> vmcnt(0);
    // tap2 wait: outstanding = W(tap2)[4 oldest] + X(cc+1)[5] -> vmcnt(5) keeps
    // the next c-block's X prefetch in flight across the barrier.
#pragma unroll 1
    for (int cc = 0; cc < 8; ++cc) {
        const int xb = cc & 1;
        const int wb0 = cc & 1, wb1 = wb0 ^ 1;
        const unsigned short* Xb = XtS + xb * 16512;
        const int kW1 = 262144 + cc * 64;   // W koff for tap1 of this cc
        const int kW2 = 524288 + cc * 64;   // tap2
        const int kW0n = cc * 64 + 64;      // tap0 of cc+1
        const int xoffn = cc * 64 + 64;     // X cols of cc+1
        const bool more = (cc < 7);

        VMWAIT(0);
        kt_body<0>(acc, WtS + wb0 * 16384, Xb, wm, wn, q, lr,
            [&]{ issueW(wb1, 0, kW1); },
            [&]{ issueW(wb1, 1, kW1); },
            [&]{ issueW(wb1, 2, kW1); issueW(wb1, 3, kW1); },
            [&]{});

        VMWAIT(0);
        kt_body<1>(acc, WtS + wb1 * 16384, Xb, wm, wn, q, lr,
            [&]{ issueW(wb0, 0, kW2); issueW(wb0, 1, kW2); },
            [&]{ issueW(wb0, 2, kW2); issueW(wb0, 3, kW2); },
            [&]{ if (more) { issueX(xb ^ 1, 0, xoffn); issueX(xb ^ 1, 1, xoffn);
                             issueX(xb ^ 1, 2, xoffn); issueX(xb ^ 1, 3, xoffn); } },
            [&]{ if (more) issueXe(xb ^ 1, xoffn); });

        if (more) { VMWAIT(5); } else { VMWAIT(0); }
        kt_body<2>(acc, WtS + wb0 * 16384, Xb, wm, wn, q, lr,
            [&]{ if (more) issueW(wb1, 0, kW0n); },
            [&]{ if (more) issueW(wb1, 1, kW0n); },
            [&]{ if (more) { issueW(wb1, 2, kW0n); issueW(wb1, 3, kW0n); } },
            [&]{});
    }

    // ---- epilogue: D col = lane&15 = p, row = q*4 + reg = f ----
    const int fbase = m0 + wm * 128 + q * 4;
    const int pbase = n0 + wn * 64 + lr;
    if (mode == 0) {
        unsigned short* dst = (unsigned short*)j.dst;
#pragma unroll
        for (int i = 0; i < 8; ++i) {
            int f = fbase + i * 16;
            float4 bv = *(const float4*)(j.bias + f);
#pragma unroll
            for (int jj = 0; jj < 4; ++jj) {
                int p = pbase + jj * 16;
                ushort4 o;
                o.x = f2bf(fmaxf(acc[i][jj][0] + bv.x, 0.f));
                o.y = f2bf(fmaxf(acc[i][jj][1] + bv.y, 0.f));
                o.z = f2bf(fmaxf(acc[i][jj][2] + bv.z, 0.f));
                o.w = f2bf(fmaxf(acc[i][jj][3] + bv.w, 0.f));
                *(ushort4*)(dst + (long)p * C_ + f) = o;
            }
        }
    } else {
        float* dst = (float*)j.dst;
#pragma unroll
        for (int jj = 0; jj < 4; ++jj) {
            float s = 0.f;
#pragma unroll
            for (int i = 0; i < 8; ++i) {
                int f = fbase + i * 16;
                float4 bv = *(const float4*)(j.bias + f);
                float4 wv = *(const float4*)(j.wl + f);
                s += fmaxf(acc[i][jj][0] + bv.x, 0.f) * wv.x;
                s += fmaxf(acc[i][jj][1] + bv.y, 0.f) * wv.y;
                s += fmaxf(acc[i][jj][2] + bv.z, 0.f) * wv.z;
                s += fmaxf(acc[i][jj][3] + bv.w, 0.f) * wv.w;
            }
            s += __shfl_xor(s, 16, 64);
            s += __shfl_xor(s, 32, 64);
            if (l < 16) atomicAdd(dst + pbase + jj * 16, s);
        }
    }
}

// ---------------------------------------------------------------------------
extern "C" void kernel_launch(void* const* d_in, const int* in_sizes, int n_in,
                              void* d_out, int out_size, void* d_ws, size_t ws_size,
                              hipStream_t stream) {
    const float* H    = (const float*)d_in[0];
    const int*   Dgt  = (const int*)d_in[1];
    const float* Pgt  = (const float*)d_in[2];
    const float* Egt  = (const float*)d_in[3];
    const float* dp_w1 = (const float*)d_in[4];
    const float* dp_b1 = (const float*)d_in[5];
    const float* dp_w2 = (const float*)d_in[6];
    const float* dp_b2 = (const float*)d_in[7];
    const float* dp_wl = (const float*)d_in[8];
    const float* dp_bl = (const float*)d_in[9];
    const float* pp_w1 = (const float*)d_in[10];
    const float* pp_b1 = (const float*)d_in[11];
    const float* pp_w2 = (const float*)d_in[12];
    const float* pp_b2 = (const float*)d_in[13];
    const float* pp_wl = (const float*)d_in[14];
    const float* pp_bl = (const float*)d_in[15];
    const float* ep_w1 = (const float*)d_in[16];
    const float* ep_b1 = (const float*)d_in[17];
    const float* ep_w2 = (const float*)d_in[18];
    const float* ep_b2 = (const float*)d_in[19];
    const float* ep_wl = (const float*)d_in[20];
    const float* ep_bl = (const float*)d_in[21];
    const float* pitch_w  = (const float*)d_in[22];
    const float* pitch_b  = (const float*)d_in[23];
    const float* energy_w = (const float*)d_in[24];
    const float* energy_b = (const float*)d_in[25];

    float* out     = (float*)d_out;
    float* H_adapt = out;                       // 16*2048*512 = 16,777,216
    float* D_pred  = out + 16777216;            // 16*512 = 8192
    float* P_pred  = out + 16785408;            // 16*2048 = 32768
    float* E_pred  = out + 16818176;            // 16*2048 = 32768

    // ws_size is call-invariant, so this layout choice is graph-stable.
    const bool par = ws_size >= 94000000ull;    // parallel-ep plan needs ~89.1 MiB

    char* ws = (char*)d_ws;
    size_t off = 0;
    unsigned short* wpack = (unsigned short*)(ws + off); off += 6UL * 786432UL * 2UL;  // 9.4 MB
    unsigned short* Hbf   = (unsigned short*)(ws + off); off += 4194304UL * 2UL;       // 8 MB
    unsigned short* h1a   = (unsigned short*)(ws + off); off += 16777216UL * 2UL;      // 33.5 MB (pp)
    unsigned short* h1b   = par ? (unsigned short*)(ws + off) : h1a;                   // ep
    if (par) off += 16777216UL * 2UL;
    unsigned short* h1dp  = (unsigned short*)(ws + off); off += 4194304UL * 2UL;       // 8 MB
    unsigned short* zrow  = (unsigned short*)(ws + off); off += 512UL * 2UL;
    off = (off + 255) & ~(size_t)255;
    int* ridx_exp = (int*)(ws + off); off += (size_t)B_ * T_ * 4;

    hipLaunchKernelGGL(prep_kernel, dim3(10546), dim3(256), 0, stream,
                       dp_w1, dp_w2, pp_w1, pp_w2, ep_w1, ep_w2, wpack, H, Hbf, zrow,
                       Dgt, ridx_exp, D_pred, P_pred, E_pred, dp_bl, pp_bl, ep_bl);

    // nxshift = log2(position tiles at BN=256): pp 32768/256=128 -> 7; dp 8192/256=32 -> 5
    ConvJob j_pp1 = { Hbf,  ridx_exp, 11,  9, wpack + 2UL * 786432, pp_b1, nullptr, h1a,    7 };
    ConvJob j_ep1 = { Hbf,  ridx_exp, 11,  9, wpack + 4UL * 786432, ep_b1, nullptr, h1b,    7 };
    ConvJob j_dp1 = { Hbf,  nullptr,   9,  9, wpack + 0UL * 786432, dp_b1, nullptr, h1dp,   5 };
    ConvJob j_pp2 = { h1a,  nullptr,  11, 11, wpack + 3UL * 786432, pp_b2, pp_wl,  P_pred, 7 };
    ConvJob j_ep2 = { h1b,  nullptr,  11, 11, wpack + 5UL * 786432, ep_b2, ep_wl,  E_pred, 7 };
    ConvJob j_dp2 = { h1dp, nullptr,   9,  9, wpack + 1UL * 786432, dp_b2, dp_wl,  D_pred, 5 };

    const unsigned lds_bytes = 131584;   // 2x32KB W + 2x33KB X

    if (par) {
        // conv1 all three (256+256+64=576) + half of adapt (512)
        hipLaunchKernelGGL(mega_kernel, dim3(576 + 512), dim3(512), lds_bytes, stream,
                           j_pp1, j_ep1, j_dp1, 256, 512, 576, 0, 0, zrow,
                           H, ridx_exp, Pgt, Egt, pitch_w, pitch_b, energy_w, energy_b, H_adapt);
        // conv2 + fused final linear + second half of adapt
        hipLaunchKernelGGL(mega_kernel, dim3(576 + 512), dim3(512), lds_bytes, stream,
                           j_pp2, j_ep2, j_dp2, 256, 512, 576, 1, 512, zrow,
                           H, ridx_exp, Pgt, Egt, pitch_w, pitch_b, energy_w, energy_b, H_adapt);
    } else {
        // serialized ep (h1b aliases h1a): pp+dp first (+all adapt), then ep
        hipLaunchKernelGGL(mega_kernel, dim3(320 + 1024), dim3(512), lds_bytes, stream,
                           j_pp1, j_dp1, j_dp1, 256, 320, 320, 0, 0, zrow,
                           H, ridx_exp, Pgt, Egt, pitch_w, pitch_b, energy_w, energy_b, H_adapt);
        hipLaunchKernelGGL(mega_kernel, dim3(320), dim3(512), lds_bytes, stream,
                           j_pp2, j_dp2, j_dp2, 256, 320, 320, 1, 0, zrow,
                           H, ridx_exp, Pgt, Egt, pitch_w, pitch_b, energy_w, energy_b, H_adapt);
        hipLaunchKernelGGL(mega_kernel, dim3(256), dim3(512), lds_bytes, stream,
                           j_ep1, j_ep1, j_ep1, 256, 256, 256, 0, 0, zrow,
                           H, ridx_exp, Pgt, Egt, pitch_w, pitch_b, energy_w, energy_b, H_adapt);
        hipLaunchKernelGGL(mega_kernel, dim3(256), dim3(512), lds_bytes, stream,
                           j_ep2, j_ep2, j_ep2, 256, 256, 256, 1, 0, zrow,
                           H, ridx_exp, Pgt, Egt, pitch_w, pitch_b, energy_w, energy_b, H_adapt);
    }
}

// Round 4
// 376.237 us; speedup vs baseline: 1.3691x; 1.3691x over previous
//
#include <hip/hip_runtime.h>

// VarianceAdaptor: B=16, S=512, C(D_MODEL)=F(FILTER)=512, K=3, T(MAX_FRAMES)=2048
#define B_ 16
#define S_ 512
#define C_ 512
#define T_ 2048

typedef __attribute__((ext_vector_type(8))) short short8;
typedef __attribute__((ext_vector_type(4))) float floatx4;

__device__ __forceinline__ unsigned short f2bf(float x) {
    union { float f; unsigned u; } c; c.f = x;
    unsigned r = (c.u + 0x7fffu + ((c.u >> 16) & 1u)) >> 16;
    return (unsigned short)r;
}

// async global->LDS, 16B per lane; lds dest = wave-uniform base + lane*16
__device__ __forceinline__ void gld_lds16(void* l, const void* g) {
    __builtin_amdgcn_global_load_lds(
        (const __attribute__((address_space(1))) void*)g,
        (__attribute__((address_space(3))) void*)l, 16, 0, 0);
}

// ---------------------------------------------------------------------------
// Fused prep (unchanged): pack 6 conv weights (F,C,3)fp32 -> (3,F,C)bf16,
// cast H->bf16, zero zrow, length-regulator rowidx, fill preds w/ final bias.
__global__ void prep_kernel(const float* __restrict__ w0, const float* __restrict__ w1,
                            const float* __restrict__ w2, const float* __restrict__ w3,
                            const float* __restrict__ w4, const float* __restrict__ w5,
                            unsigned short* __restrict__ wpack,
                            const float* __restrict__ H, unsigned short* __restrict__ Hbf,
                            unsigned short* __restrict__ zrow,
                            const int* __restrict__ Dgt, int* __restrict__ ridx,
                            float* __restrict__ Dp, float* __restrict__ Pp, float* __restrict__ Ep,
                            const float* __restrict__ dbl, const float* __restrict__ pbl,
                            const float* __restrict__ ebl) {
    __shared__ int cs[S_];
    __shared__ int ps[256];
    int blk = blockIdx.x;
    int tid = threadIdx.x;
    if (blk < 6144) {                      // weight pack: 6 x 1024 blocks
        int which = blk >> 10;
        const float* w = which == 0 ? w0 : which == 1 ? w1 : which == 2 ? w2
                       : which == 3 ? w3 : which == 4 ? w4 : w5;
        unsigned short* wp = wpack + (long)which * 786432;
        int i = (blk & 1023) * 256 + tid;   // i over F*C = 262144
        const float* s = w + (long)i * 3;
        wp[i]          = f2bf(s[0]);
        wp[i + 262144] = f2bf(s[1]);
        wp[i + 524288] = f2bf(s[2]);
    } else if (blk < 10240) {              // H fp32 -> bf16: 4096 blocks x 4 elems
        int i = (blk - 6144) * 256 + tid;
        float4 v = *(const float4*)(H + (long)i * 4);
        ushort4 o;
        o.x = f2bf(v.x); o.y = f2bf(v.y); o.z = f2bf(v.z); o.w = f2bf(v.w);
        *(ushort4*)(Hbf + (long)i * 4) = o;
    } else if (blk < 10242) {              // zrow: 2 blocks
        zrow[(blk - 10240) * 256 + tid] = 0;
    } else if (blk < 10258) {              // expand rowidx: 16 blocks (one/batch)
        int b = blk - 10242;
        int t2 = tid * 2;
        int d0 = Dgt[b * S_ + t2], d1 = Dgt[b * S_ + t2 + 1];
        int a0 = d0 < 0 ? 0 : d0, a1 = d1 < 0 ? 0 : d1;
        ps[tid] = a0 + a1;
        __syncthreads();
        for (int off = 1; off < 256; off <<= 1) {
            int v = (tid >= off) ? ps[tid - off] : 0;
            __syncthreads();
            ps[tid] += v;
            __syncthreads();
        }
        int incl = ps[tid];
        cs[t2] = incl - a1;
        cs[t2 + 1] = incl;
        __syncthreads();
        int total = cs[S_ - 1];
        int limit = total < T_ ? total : T_;
        for (int t = tid; t < T_; t += 256) {
            int lo = 0, hi = S_;
            while (lo < hi) { int mid = (lo + hi) >> 1; if (cs[mid] <= t) lo = mid + 1; else hi = mid; }
            if (lo > S_ - 1) lo = S_ - 1;
            ridx[b * T_ + t] = (t < limit) ? lo : -1;
        }
    } else {                               // fill preds: 288 blocks
        int i = (blk - 10258) * 256 + tid;
        if (i < 8192) Dp[i] = dbl[0];
        else if (i < 40960) Pp[i - 8192] = pbl[0];
        else Ep[i - 40960] = ebl[0];
    }
}

// ---------------------------------------------------------------------------
// 256x256-tile 8-wave conv-GEMM, counted-vmcnt pipeline, 2 syncs per K-tile.
//   D[f, p] = sum_{tap, c} W[tap][f][c] * X[row(p + tap - 1)][c]
// K-tiles (BK=64) ordered c-block-major (cc=0..7), tap-minor (0..2).  X staged
// once per cc (parity cc&1); W per kt (parity (cc+tap)&1).  Each kt:
//   VMWAIT(n) ; s_barrier ; issue next-kt staging ; 24 ds_read_b128 + 64 MFMA
// (straight-line, compiler-scheduled — no intra-kt barriers).  Waits counted
// so every load has >= 1 full kt of slack; X prefetch (5 ops) rides across
// tap2's vmcnt(5) and is only drained 2 kts after issue.
// LDS rows of 64 shorts (8 x 16B chunks); chunk c8 of row r holds global
// chunk c8 ^ (r&7) (bank swizzle, 0 conflicts); linear LDS dest for
// global_load_lds, inverse-swizzled global source.
struct ConvJob {
    const unsigned short* X;    // bf16 rows [B << Bshift][C]
    const int* ridx;            // per (b,t) row-in-batch, or nullptr = identity
    int Lshift;                 // log2 positions per batch
    int Bshift;                 // log2 rows per batch of X
    const unsigned short* wp;   // [3][512][512] bf16
    const float* bias;
    const float* wl;
    void* dst;
    int nxshift;                // log2 of position tiles (BN=256)
};

template <int TAP>
__device__ __forceinline__ void compute_kt(
    floatx4 (&acc)[8][4],
    const unsigned short* Wb, const unsigned short* Xb,
    int wm, int wn, int q, int lr)
{
    // B (X) fragments: rows wn*64 + jj*16 + lr + TAP, chunks (k*4+q)^(row&7)
    short8 bfr[4][2];
#pragma unroll
    for (int jj = 0; jj < 4; ++jj) {
        const int xr = wn * 64 + jj * 16 + lr + TAP;
        const unsigned short* xp = Xb + xr * 64;
        const int sX = xr & 7;
        bfr[jj][0] = *(const short8*)(xp + ((q ^ sX) * 8));
        bfr[jj][1] = *(const short8*)(xp + (((4 + q) ^ sX) * 8));
    }
    const int sA = lr & 7;   // W row = wm*128 + ph*32 + (0|16) + lr ; row&7 == lr&7
#pragma unroll
    for (int ph = 0; ph < 4; ++ph) {
        const unsigned short* ap0 = Wb + (wm * 128 + ph * 32 + lr) * 64;
        const unsigned short* ap1 = ap0 + 1024;         // +16 rows
        short8 a00 = *(const short8*)(ap0 + ((q ^ sA) * 8));
        short8 a01 = *(const short8*)(ap0 + (((4 + q) ^ sA) * 8));
        short8 a10 = *(const short8*)(ap1 + ((q ^ sA) * 8));
        short8 a11 = *(const short8*)(ap1 + (((4 + q) ^ sA) * 8));
#pragma unroll
        for (int jj = 0; jj < 4; ++jj) {
            acc[ph*2][jj]   = __builtin_amdgcn_mfma_f32_16x16x32_bf16(a00, bfr[jj][0], acc[ph*2][jj],   0, 0, 0);
            acc[ph*2][jj]   = __builtin_amdgcn_mfma_f32_16x16x32_bf16(a01, bfr[jj][1], acc[ph*2][jj],   0, 0, 0);
            acc[ph*2+1][jj] = __builtin_amdgcn_mfma_f32_16x16x32_bf16(a10, bfr[jj][0], acc[ph*2+1][jj], 0, 0, 0);
            acc[ph*2+1][jj] = __builtin_amdgcn_mfma_f32_16x16x32_bf16(a11, bfr[jj][1], acc[ph*2+1][jj], 0, 0, 0);
        }
    }
}

// counted wait + publish barrier at K-tile start
#define VMWAIT(n) do { \
    asm volatile("s_waitcnt vmcnt(" #n ")" ::: "memory"); \
    __builtin_amdgcn_sched_barrier(0); \
    __builtin_amdgcn_s_barrier(); \
    __builtin_amdgcn_sched_barrier(0); \
} while (0)

__global__ __launch_bounds__(512, 2) void mega_kernel(
    ConvJob j0, ConvJob j1, ConvJob j2, int e0, int e1, int e2, int mode, int aoff,
    const unsigned short* __restrict__ zrow,
    const float* __restrict__ H, const int* __restrict__ aridx,
    const float* __restrict__ Pgt, const float* __restrict__ Egt,
    const float* __restrict__ pw, const float* __restrict__ pb,
    const float* __restrict__ ew, const float* __restrict__ eb,
    float* __restrict__ aout)
{
    extern __shared__ unsigned short lds[];   // 131584 B: W[2][16384] + X[2][16512] shorts
    const int bx = blockIdx.x;
    const int tid = threadIdx.x;

    if (bx >= e2) {
        // ---- adapt path: 512-thread blocks, aoff selects half ----
        int ab = bx - e2 + aoff;
#pragma unroll
        for (int it = 0; it < 8; ++it) {
            int i = ab * 512 + tid + it * 524288;
            int f4 = i & 127;
            int p  = i >> 7;
            int b  = p >> 11;
            int r  = aridx[p];
            float pg = Pgt[p], eg = Egt[p];
            int f = f4 << 2;
            float4 pwv = *(const float4*)(pw + f);
            float4 pbv = *(const float4*)(pb + f);
            float4 ewv = *(const float4*)(ew + f);
            float4 ebv = *(const float4*)(eb + f);
            float4 h = make_float4(0.f, 0.f, 0.f, 0.f);
            if (r >= 0) h = *(const float4*)(H + ((long)b * S_ + r) * C_ + f);
            float4 o;
            o.x = h.x + pg * pwv.x + pbv.x + eg * ewv.x + ebv.x;
            o.y = h.y + pg * pwv.y + pbv.y + eg * ewv.y + ebv.y;
            o.z = h.z + pg * pwv.z + pbv.z + eg * ewv.z + ebv.z;
            o.w = h.w + pg * pwv.w + pbv.w + eg * ewv.w + ebv.w;
            *(float4*)(aout + (long)p * C_ + f) = o;
        }
        return;
    }

    ConvJob j;
    int local;
    if (bx < e0)      { j = j0; local = bx; }
    else if (bx < e1) { j = j1; local = bx - e0; }
    else              { j = j2; local = bx - e1; }
    const int m0 = (local >> j.nxshift) * 256;
    const int n0 = (local & ((1 << j.nxshift) - 1)) * 256;
    const int L = 1 << j.Lshift;
    const int b = n0 >> j.Lshift;
    const int t0 = n0 & (L - 1);

    unsigned short* WtS = lds;            // [2][16384]
    unsigned short* XtS = lds + 32768;    // [2][16512]  (258 rows x 64)
    char* WtB = (char*)WtS;
    char* XtB = (char*)XtS;

    const int w = tid >> 6, l = tid & 63;
    const int q = l >> 4, lr = l & 15;
    const int wm = w & 1, wn = w >> 1;

    floatx4 acc[8][4];
#pragma unroll
    for (int i = 0; i < 8; ++i)
#pragma unroll
        for (int jj = 0; jj < 4; ++jj) acc[i][jj] = (floatx4){0.f, 0.f, 0.f, 0.f};

    // ---- staging source pointers (16B chunks, inverse-swizzled source) ----
    // instr qq stages chunk ch = qq*512 + w*64 + l: row = ch>>3, c8 = l&7.
    const int swz = ((l & 7) ^ ((l >> 3) & 7)) * 8;
    auto xrowp = [&](int r) -> const unsigned short* {
        int t = t0 - 1 + r;
        if (t < 0 || t >= L) return zrow;
        int rr = j.ridx ? j.ridx[(b << j.Lshift) + t] : t;
        if (rr < 0) return zrow;
        return j.X + ((long)(b << j.Bshift) + rr) * C_;
    };
    const unsigned short* wsrc[4];
    const unsigned short* xsrc[4];
#pragma unroll
    for (int qq = 0; qq < 4; ++qq) {
        int row = qq * 64 + w * 8 + (l >> 3);
        wsrc[qq] = j.wp + (long)(m0 + row) * C_ + swz;
        xsrc[qq] = xrowp(row) + swz;
    }
    // extra X rows 256,257: chunks ch_e = w*2 + lane(0,1)
    const int ch_e = w * 2 + (l & 1);
    const int row_e = 256 + (ch_e >> 3);
    const unsigned short* xsrcE = xrowp(row_e) + (((ch_e & 7) ^ (row_e & 7)) * 8);

    auto issueW = [&](int buf, int qq, int koff) {
        gld_lds16(WtB + buf * 32768 + qq * 8192 + w * 1024, wsrc[qq] + koff);
    };
    auto issueX = [&](int buf, int qq, int xoff) {
        gld_lds16(XtB + buf * 33024 + qq * 8192 + w * 1024, xsrc[qq] + xoff);
    };
    auto issueXe = [&](int buf, int xoff) {
        if (l < 2) gld_lds16(XtB + buf * 33024 + 32768 + w * 32, xsrcE + xoff);
    };

    // ---- prologue: X(cc=0) [5 ops] + W(kt0: tap0,cc0) [4 ops] ----
    issueX(0, 0, 0); issueX(0, 1, 0); issueX(0, 2, 0); issueX(0, 3, 0); issueXe(0, 0);
    issueW(0, 0, 0); issueW(0, 1, 0); issueW(0, 2, 0); issueW(0, 3, 0);

    // ---- main loop.  W parity of kt (cc,tap) = (cc+tap)&1; X parity = cc&1.
    // Waits at kt start (outstanding per wave -> required):
    //  tap0: X(cc)[5, 2 kts old] + W(t0)[4, 1 kt old]   -> vmcnt(0)
    //  tap1: W(t1)[4, 1 kt old]                         -> vmcnt(0)
    //  tap2: W(t2)[4, 1 kt old] + X(cc+1)[5, just sent] -> vmcnt(5)  (keep X in flight)
#pragma unroll 1
    for (int cc = 0; cc < 8; ++cc) {
        const int xb = cc & 1;
        const unsigned short* Xb = XtS + xb * 16512;
        const unsigned short* W0 = WtS + xb * 16384;          // parity cc&1 (tap0, tap2)
        const unsigned short* W1 = WtS + (xb ^ 1) * 16384;    // parity (cc+1)&1 (tap1)
        const int kW1 = 262144 + cc * 64;   // W koff tap1
        const int kW2 = 524288 + cc * 64;   // W koff tap2
        const int kW0n = cc * 64 + 64;      // W koff tap0 of cc+1
        const int xoffn = cc * 64 + 64;     // X cols of cc+1
        const bool more = (cc < 7);

        // tap0: read W0; stage W(t1) -> parity xb^1
        VMWAIT(0);
        issueW(xb ^ 1, 0, kW1); issueW(xb ^ 1, 1, kW1);
        issueW(xb ^ 1, 2, kW1); issueW(xb ^ 1, 3, kW1);
        compute_kt<0>(acc, W0, Xb, wm, wn, q, lr);

        // tap1: read W1; stage W(t2) -> parity xb; stage X(cc+1)
        VMWAIT(0);
        issueW(xb, 0, kW2); issueW(xb, 1, kW2);
        issueW(xb, 2, kW2); issueW(xb, 3, kW2);
        if (more) {
            issueX(xb ^ 1, 0, xoffn); issueX(xb ^ 1, 1, xoffn);
            issueX(xb ^ 1, 2, xoffn); issueX(xb ^ 1, 3, xoffn);
            issueXe(xb ^ 1, xoffn);
        }
        compute_kt<1>(acc, W1, Xb, wm, wn, q, lr);

        // tap2: read W0 (now holds W(t2)); stage W(t0,cc+1) -> parity xb^1
        if (more) { VMWAIT(5); } else { VMWAIT(0); }
        if (more) {
            issueW(xb ^ 1, 0, kW0n); issueW(xb ^ 1, 1, kW0n);
            issueW(xb ^ 1, 2, kW0n); issueW(xb ^ 1, 3, kW0n);
        }
        compute_kt<2>(acc, W0, Xb, wm, wn, q, lr);
    }

    // ---- epilogue: D col = lane&15 = p, row = q*4 + reg = f ----
    const int fbase = m0 + wm * 128 + q * 4;
    const int pbase = n0 + wn * 64 + lr;
    if (mode == 0) {
        unsigned short* dst = (unsigned short*)j.dst;
#pragma unroll
        for (int i = 0; i < 8; ++i) {
            int f = fbase + i * 16;
            float4 bv = *(const float4*)(j.bias + f);
#pragma unroll
            for (int jj = 0; jj < 4; ++jj) {
                int p = pbase + jj * 16;
                ushort4 o;
                o.x = f2bf(fmaxf(acc[i][jj][0] + bv.x, 0.f));
                o.y = f2bf(fmaxf(acc[i][jj][1] + bv.y, 0.f));
                o.z = f2bf(fmaxf(acc[i][jj][2] + bv.z, 0.f));
                o.w = f2bf(fmaxf(acc[i][jj][3] + bv.w, 0.f));
                *(ushort4*)(dst + (long)p * C_ + f) = o;
            }
        }
    } else {
        float* dst = (float*)j.dst;
#pragma unroll
        for (int jj = 0; jj < 4; ++jj) {
            float s = 0.f;
#pragma unroll
            for (int i = 0; i < 8; ++i) {
                int f = fbase + i * 16;
                float4 bv = *(const float4*)(j.bias + f);
                float4 wv = *(const float4*)(j.wl + f);
                s += fmaxf(acc[i][jj][0] + bv.x, 0.f) * wv.x;
                s += fmaxf(acc[i][jj][1] + bv.y, 0.f) * wv.y;
                s += fmaxf(acc[i][jj][2] + bv.z, 0.f) * wv.z;
                s += fmaxf(acc[i][jj][3] + bv.w, 0.f) * wv.w;
            }
            s += __shfl_xor(s, 16, 64);
            s += __shfl_xor(s, 32, 64);
            if (l < 16) atomicAdd(dst + pbase + jj * 16, s);
        }
    }
}

// ---------------------------------------------------------------------------
extern "C" void kernel_launch(void* const* d_in, const int* in_sizes, int n_in,
                              void* d_out, int out_size, void* d_ws, size_t ws_size,
                              hipStream_t stream) {
    const float* H    = (const float*)d_in[0];
    const int*   Dgt  = (const int*)d_in[1];
    const float* Pgt  = (const float*)d_in[2];
    const float* Egt  = (const float*)d_in[3];
    const float* dp_w1 = (const float*)d_in[4];
    const float* dp_b1 = (const float*)d_in[5];
    const float* dp_w2 = (const float*)d_in[6];
    const float* dp_b2 = (const float*)d_in[7];
    const float* dp_wl = (const float*)d_in[8];
    const float* dp_bl = (const float*)d_in[9];
    const float* pp_w1 = (const float*)d_in[10];
    const float* pp_b1 = (const float*)d_in[11];
    const float* pp_w2 = (const float*)d_in[12];
    const float* pp_b2 = (const float*)d_in[13];
    const float* pp_wl = (const float*)d_in[14];
    const float* pp_bl = (const float*)d_in[15];
    const float* ep_w1 = (const float*)d_in[16];
    const float* ep_b1 = (const float*)d_in[17];
    const float* ep_w2 = (const float*)d_in[18];
    const float* ep_b2 = (const float*)d_in[19];
    const float* ep_wl = (const float*)d_in[20];
    const float* ep_bl = (const float*)d_in[21];
    const float* pitch_w  = (const float*)d_in[22];
    const float* pitch_b  = (const float*)d_in[23];
    const float* energy_w = (const float*)d_in[24];
    const float* energy_b = (const float*)d_in[25];

    float* out     = (float*)d_out;
    float* H_adapt = out;                       // 16*2048*512 = 16,777,216
    float* D_pred  = out + 16777216;            // 16*512 = 8192
    float* P_pred  = out + 16785408;            // 16*2048 = 32768
    float* E_pred  = out + 16818176;            // 16*2048 = 32768

    // ws_size is call-invariant, so this layout choice is graph-stable.
    const bool par = ws_size >= 94000000ull;    // parallel-ep plan needs ~89.1 MiB

    char* ws = (char*)d_ws;
    size_t off = 0;
    unsigned short* wpack = (unsigned short*)(ws + off); off += 6UL * 786432UL * 2UL;  // 9.4 MB
    unsigned short* Hbf   = (unsigned short*)(ws + off); off += 4194304UL * 2UL;       // 8 MB
    unsigned short* h1a   = (unsigned short*)(ws + off); off += 16777216UL * 2UL;      // 33.5 MB (pp)
    unsigned short* h1b   = par ? (unsigned short*)(ws + off) : h1a;                   // ep
    if (par) off += 16777216UL * 2UL;
    unsigned short* h1dp  = (unsigned short*)(ws + off); off += 4194304UL * 2UL;       // 8 MB
    unsigned short* zrow  = (unsigned short*)(ws + off); off += 512UL * 2UL;
    off = (off + 255) & ~(size_t)255;
    int* ridx_exp = (int*)(ws + off); off += (size_t)B_ * T_ * 4;

    hipLaunchKernelGGL(prep_kernel, dim3(10546), dim3(256), 0, stream,
                       dp_w1, dp_w2, pp_w1, pp_w2, ep_w1, ep_w2, wpack, H, Hbf, zrow,
                       Dgt, ridx_exp, D_pred, P_pred, E_pred, dp_bl, pp_bl, ep_bl);

    // nxshift = log2(position tiles at BN=256): pp 32768/256=128 -> 7; dp 8192/256=32 -> 5
    ConvJob j_pp1 = { Hbf,  ridx_exp, 11,  9, wpack + 2UL * 786432, pp_b1, nullptr, h1a,    7 };
    ConvJob j_ep1 = { Hbf,  ridx_exp, 11,  9, wpack + 4UL * 786432, ep_b1, nullptr, h1b,    7 };
    ConvJob j_dp1 = { Hbf,  nullptr,   9,  9, wpack + 0UL * 786432, dp_b1, nullptr, h1dp,   5 };
    ConvJob j_pp2 = { h1a,  nullptr,  11, 11, wpack + 3UL * 786432, pp_b2, pp_wl,  P_pred, 7 };
    ConvJob j_ep2 = { h1b,  nullptr,  11, 11, wpack + 5UL * 786432, ep_b2, ep_wl,  E_pred, 7 };
    ConvJob j_dp2 = { h1dp, nullptr,   9,  9, wpack + 1UL * 786432, dp_b2, dp_wl,  D_pred, 5 };

    const unsigned lds_bytes = 131584;   // 2x32KB W + 2x33KB X

    if (par) {
        // conv1 all three (256+256+64=576) + half of adapt (512)
        hipLaunchKernelGGL(mega_kernel, dim3(576 + 512), dim3(512), lds_bytes, stream,
                           j_pp1, j_ep1, j_dp1, 256, 512, 576, 0, 0, zrow,
                           H, ridx_exp, Pgt, Egt, pitch_w, pitch_b, energy_w, energy_b, H_adapt);
        // conv2 + fused final linear + second half of adapt
        hipLaunchKernelGGL(mega_kernel, dim3(576 + 512), dim3(512), lds_bytes, stream,
                           j_pp2, j_ep2, j_dp2, 256, 512, 576, 1, 512, zrow,
                           H, ridx_exp, Pgt, Egt, pitch_w, pitch_b, energy_w, energy_b, H_adapt);
    } else {
        // serialized ep (h1b aliases h1a): pp+dp first (+all adapt), then ep
        hipLaunchKernelGGL(mega_kernel, dim3(320 + 1024), dim3(512), lds_bytes, stream,
                           j_pp1, j_dp1, j_dp1, 256, 320, 320, 0, 0, zrow,
                           H, ridx_exp, Pgt, Egt, pitch_w, pitch_b, energy_w, energy_b, H_adapt);
        hipLaunchKernelGGL(mega_kernel, dim3(320), dim3(512), lds_bytes, stream,
                           j_pp2, j_dp2, j_dp2, 256, 320, 320, 1, 0, zrow,
                           H, ridx_exp, Pgt, Egt, pitch_w, pitch_b, energy_w, energy_b, H_adapt);
        hipLaunchKernelGGL(mega_kernel, dim3(256), dim3(512), lds_bytes, stream,
                           j_ep1, j_ep1, j_ep1, 256, 256, 256, 0, 0, zrow,
                           H, ridx_exp, Pgt, Egt, pitch_w, pitch_b, energy_w, energy_b, H_adapt);
        hipLaunchKernelGGL(mega_kernel, dim3(256), dim3(512), lds_bytes, stream,
                           j_ep2, j_ep2, j_ep2, 256, 256, 256, 1, 0, zrow,
                           H, ridx_exp, Pgt, Egt, pitch_w, pitch_b, energy_w, energy_b, H_adapt);
    }
}

// Round 6
// 352.918 us; speedup vs baseline: 1.4595x; 1.0661x over previous
//
#include <hip/hip_runtime.h>

// VarianceAdaptor: B=16, S=512, C(D_MODEL)=F(FILTER)=512, K=3, T(MAX_FRAMES)=2048
#define B_ 16
#define S_ 512
#define C_ 512
#define T_ 2048

typedef __attribute__((ext_vector_type(8))) short short8;
typedef __attribute__((ext_vector_type(4))) float floatx4;

__device__ __forceinline__ unsigned short f2bf(float x) {
    union { float f; unsigned u; } c; c.f = x;
    unsigned r = (c.u + 0x7fffu + ((c.u >> 16) & 1u)) >> 16;
    return (unsigned short)r;
}

// async global->LDS, 16B per lane; lds dest = wave-uniform base + lane*16
__device__ __forceinline__ void gld_lds16(void* l, const void* g) {
    __builtin_amdgcn_global_load_lds(
        (const __attribute__((address_space(1))) void*)g,
        (__attribute__((address_space(3))) void*)l, 16, 0, 0);
}

// ---------------------------------------------------------------------------
// Fused prep (unchanged): pack 6 conv weights (F,C,3)fp32 -> (3,F,C)bf16,
// cast H->bf16, zero zrow, length-regulator rowidx, fill preds w/ final bias.
__global__ void prep_kernel(const float* __restrict__ w0, const float* __restrict__ w1,
                            const float* __restrict__ w2, const float* __restrict__ w3,
                            const float* __restrict__ w4, const float* __restrict__ w5,
                            unsigned short* __restrict__ wpack,
                            const float* __restrict__ H, unsigned short* __restrict__ Hbf,
                            unsigned short* __restrict__ zrow,
                            const int* __restrict__ Dgt, int* __restrict__ ridx,
                            float* __restrict__ Dp, float* __restrict__ Pp, float* __restrict__ Ep,
                            const float* __restrict__ dbl, const float* __restrict__ pbl,
                            const float* __restrict__ ebl) {
    __shared__ int cs[S_];
    __shared__ int ps[256];
    int blk = blockIdx.x;
    int tid = threadIdx.x;
    if (blk < 6144) {                      // weight pack: 6 x 1024 blocks
        int which = blk >> 10;
        const float* w = which == 0 ? w0 : which == 1 ? w1 : which == 2 ? w2
                       : which == 3 ? w3 : which == 4 ? w4 : w5;
        unsigned short* wp = wpack + (long)which * 786432;
        int i = (blk & 1023) * 256 + tid;   // i over F*C = 262144
        const float* s = w + (long)i * 3;
        wp[i]          = f2bf(s[0]);
        wp[i + 262144] = f2bf(s[1]);
        wp[i + 524288] = f2bf(s[2]);
    } else if (blk < 10240) {              // H fp32 -> bf16: 4096 blocks x 4 elems
        int i = (blk - 6144) * 256 + tid;
        float4 v = *(const float4*)(H + (long)i * 4);
        ushort4 o;
        o.x = f2bf(v.x); o.y = f2bf(v.y); o.z = f2bf(v.z); o.w = f2bf(v.w);
        *(ushort4*)(Hbf + (long)i * 4) = o;
    } else if (blk < 10242) {              // zrow: 2 blocks
        zrow[(blk - 10240) * 256 + tid] = 0;
    } else if (blk < 10258) {              // expand rowidx: 16 blocks (one/batch)
        int b = blk - 10242;
        int t2 = tid * 2;
        int d0 = Dgt[b * S_ + t2], d1 = Dgt[b * S_ + t2 + 1];
        int a0 = d0 < 0 ? 0 : d0, a1 = d1 < 0 ? 0 : d1;
        ps[tid] = a0 + a1;
        __syncthreads();
        for (int off = 1; off < 256; off <<= 1) {
            int v = (tid >= off) ? ps[tid - off] : 0;
            __syncthreads();
            ps[tid] += v;
            __syncthreads();
        }
        int incl = ps[tid];
        cs[t2] = incl - a1;
        cs[t2 + 1] = incl;
        __syncthreads();
        int total = cs[S_ - 1];
        int limit = total < T_ ? total : T_;
        for (int t = tid; t < T_; t += 256) {
            int lo = 0, hi = S_;
            while (lo < hi) { int mid = (lo + hi) >> 1; if (cs[mid] <= t) lo = mid + 1; else hi = mid; }
            if (lo > S_ - 1) lo = S_ - 1;
            ridx[b * T_ + t] = (t < limit) ? lo : -1;
        }
    } else {                               // fill preds: 288 blocks
        int i = (blk - 10258) * 256 + tid;
        if (i < 8192) Dp[i] = dbl[0];
        else if (i < 40960) Pp[i - 8192] = pbl[0];
        else Ep[i - 40960] = ebl[0];
    }
}

// ---------------------------------------------------------------------------
// 128x128-tile 4-wave conv-GEMM, BK=32, tap-minor counted-vmcnt pipeline.
//   D[f, p] = sum_{tap, c} W[tap][f][c] * X[row(p + tap - 1)][c]
// K-tiles: c-block-major (cc=0..15, 32 c each), tap-minor (0..2).  X staged
// once per cc (parity cc&1); W per kt (parity (cc+tap)&1).  Each kt:
//   VMWAIT(n); s_barrier; issue next staging; 8 ds_read_b128 + 16 MFMA.
// vmcnt counted so every load has >= 1 full kt of slack; X prefetch (3 ops)
// rides across tap2's vmcnt(3).  LDS 33 KB -> 4 blocks/CU (launch_bounds
// (256,4) caps regs at 128; acc[4][4]=64).  Swizzle (R2-verified, 0 confl.):
// rows of 32 shorts (64B = 4 x 16B chunks); chunk c8 of row r holds global
// chunk c8 ^ ((r>>1)&3); linear LDS dest, inverse-swizzled global source.
struct ConvJob {
    const unsigned short* X;    // bf16 rows [B << Bshift][C]
    const int* ridx;            // per (b,t) row-in-batch, or nullptr = identity
    int Lshift;                 // log2 positions per batch
    int Bshift;                 // log2 rows per batch of X
    const unsigned short* wp;   // [3][512][512] bf16
    const float* bias;
    const float* wl;
    void* dst;
    int nxshift;                // log2 of position tiles (BN=128)
};

template <int TAP>
__device__ __forceinline__ void compute_kt(
    floatx4 (&acc)[4][4],
    const unsigned short* Wb, const unsigned short* Xb,
    int wm, int wn, int q, int lr)
{
    // B (X) frags: row wn*64 + jj*16 + lr + TAP; stored chunk q^((row>>1)&3)
    short8 bfr[4];
    const int sX = ((lr + TAP) >> 1) & 3;
#pragma unroll
    for (int jj = 0; jj < 4; ++jj) {
        const int xr = wn * 64 + jj * 16 + lr + TAP;
        bfr[jj] = *(const short8*)(Xb + xr * 32 + ((q ^ sX) * 8));
    }
    const int sA = (lr >> 1) & 3;
#pragma unroll
    for (int i = 0; i < 4; ++i) {
        const int rA = wm * 64 + i * 16 + lr;
        short8 a = *(const short8*)(Wb + rA * 32 + ((q ^ sA) * 8));
#pragma unroll
        for (int jj = 0; jj < 4; ++jj)
            acc[i][jj] = __builtin_amdgcn_mfma_f32_16x16x32_bf16(a, bfr[jj], acc[i][jj], 0, 0, 0);
    }
}

// counted wait + publish barrier at K-tile start
#define VMWAIT(n) do { \
    asm volatile("s_waitcnt vmcnt(" #n ")" ::: "memory"); \
    __builtin_amdgcn_sched_barrier(0); \
    __builtin_amdgcn_s_barrier(); \
    __builtin_amdgcn_sched_barrier(0); \
} while (0)

__global__ __launch_bounds__(256, 4) void mega_kernel(
    ConvJob j0, ConvJob j1, ConvJob j2, int e0, int e1, int e2, int mode, int aoff,
    const unsigned short* __restrict__ zrow,
    const float* __restrict__ H, const int* __restrict__ aridx,
    const float* __restrict__ Pgt, const float* __restrict__ Egt,
    const float* __restrict__ pw, const float* __restrict__ pb,
    const float* __restrict__ ew, const float* __restrict__ eb,
    float* __restrict__ aout)
{
    extern __shared__ unsigned short lds[];   // 33024 B: W[2][4096] + X[2][4160] shorts
    const int bx = blockIdx.x;
    const int tid = threadIdx.x;

    if (bx >= e2) {
        // ---- adapt path: aoff selects which half of the 2048-block range ----
        int ab = bx - e2 + aoff;
#pragma unroll
        for (int it = 0; it < 8; ++it) {
            int i = ab * 256 + tid + it * 524288;
            int f4 = i & 127;
            int p  = i >> 7;
            int b  = p >> 11;
            int r  = aridx[p];
            float pg = Pgt[p], eg = Egt[p];
            int f = f4 << 2;
            float4 pwv = *(const float4*)(pw + f);
            float4 pbv = *(const float4*)(pb + f);
            float4 ewv = *(const float4*)(ew + f);
            float4 ebv = *(const float4*)(eb + f);
            float4 h = make_float4(0.f, 0.f, 0.f, 0.f);
            if (r >= 0) h = *(const float4*)(H + ((long)b * S_ + r) * C_ + f);
            float4 o;
            o.x = h.x + pg * pwv.x + pbv.x + eg * ewv.x + ebv.x;
            o.y = h.y + pg * pwv.y + pbv.y + eg * ewv.y + ebv.y;
            o.z = h.z + pg * pwv.z + pbv.z + eg * ewv.z + ebv.z;
            o.w = h.w + pg * pwv.w + pbv.w + eg * ewv.w + ebv.w;
            *(float4*)(aout + (long)p * C_ + f) = o;
        }
        return;
    }

    ConvJob j;
    int local;
    if (bx < e0)      { j = j0; local = bx; }
    else if (bx < e1) { j = j1; local = bx - e0; }
    else              { j = j2; local = bx - e1; }
    const int m0 = (local >> j.nxshift) * 128;
    const int n0 = (local & ((1 << j.nxshift) - 1)) * 128;
    const int L = 1 << j.Lshift;
    const int b = n0 >> j.Lshift;
    const int t0 = n0 & (L - 1);

    unsigned short* WtS = lds;            // [2][4096]  (128 rows x 32) x 2
    unsigned short* XtS = lds + 8192;     // [2][4160]  (130 rows x 32) x 2
    char* WtB = (char*)WtS;
    char* XtB = (char*)XtS;

    const int w = tid >> 6, l = tid & 63;
    const int q = l >> 4, lr = l & 15;
    const int wm = w & 1, wn = w >> 1;

    floatx4 acc[4][4];
#pragma unroll
    for (int i = 0; i < 4; ++i)
#pragma unroll
        for (int jj = 0; jj < 4; ++jj) acc[i][jj] = (floatx4){0.f, 0.f, 0.f, 0.f};

    // ---- staging sources (16B chunks; inverse-swizzled source column) ----
    // issue qq stages chunk ch = qq*256 + tid: row = qq*64 + (tid>>2), c8 = tid&3;
    // source col-chunk = c8 ^ ((row>>1)&3) = (tid&3) ^ ((tid>>3)&3).
    const int sw = (((tid & 3) ^ ((tid >> 3) & 3))) * 8;
    auto xrowp = [&](int r) -> const unsigned short* {
        int t = t0 - 1 + r;
        if (t < 0 || t >= L) return zrow;
        int rr = j.ridx ? j.ridx[(b << j.Lshift) + t] : t;
        if (rr < 0) return zrow;
        return j.X + ((long)(b << j.Bshift) + rr) * C_;
    };
    const unsigned short* wsrc[2];
    const unsigned short* xsrc[2];
#pragma unroll
    for (int qq = 0; qq < 2; ++qq) {
        int row = qq * 64 + (tid >> 2);
        wsrc[qq] = j.wp + (long)(m0 + row) * C_ + sw;
        xsrc[qq] = xrowp(row) + sw;
    }
    // extra X rows 128,129: chunks ch_e = w*2 + l (l<2); (row_e>>1)&3 == 0
    const int ch_e = w * 2 + (l & 1);
    const unsigned short* xsrcE = xrowp(128 + (ch_e >> 2)) + (ch_e & 3) * 8;

    auto issueW = [&](int buf, int koff) {
        gld_lds16(WtB + buf * 8192 + 0 * 4096 + w * 1024, wsrc[0] + koff);
        gld_lds16(WtB + buf * 8192 + 1 * 4096 + w * 1024, wsrc[1] + koff);
    };
    auto issueX = [&](int buf, int xoff) {
        gld_lds16(XtB + buf * 8320 + 0 * 4096 + w * 1024, xsrc[0] + xoff);
        gld_lds16(XtB + buf * 8320 + 1 * 4096 + w * 1024, xsrc[1] + xoff);
        if (l < 2)
            gld_lds16(XtB + buf * 8320 + 8192 + w * 32, xsrcE + xoff);
    };

    // ---- prologue: X(cc=0) [3 ops] + W(cc0,tap0) [2 ops] ----
    issueX(0, 0);
    issueW(0, 0);

    // ---- main loop.  W parity of kt (cc,tap) = (cc+tap)&1; X parity = cc&1.
    // Waits at kt start (outstanding per wave -> count):
    //  tap0: X(cc)[3] + W(t0)[2], all >= 1 kt old      -> vmcnt(0)
    //  tap1: W(t1)[2], 1 kt old                        -> vmcnt(0)
    //  tap2: W(t2)[2, 1kt old] + X(cc+1)[3, just sent] -> vmcnt(3) keep X flying
#pragma unroll 1
    for (int cc = 0; cc < 16; ++cc) {
        const int xb = cc & 1;
        const unsigned short* Xb = XtS + xb * 4160;
        const unsigned short* W0 = WtS + xb * 4096;          // parity cc&1 (tap0, tap2)
        const unsigned short* W1 = WtS + (xb ^ 1) * 4096;    // parity (cc+1)&1 (tap1)
        const int kW1 = 262144 + cc * 32;   // W col-off tap1
        const int kW2 = 524288 + cc * 32;   // W col-off tap2
        const int kW0n = cc * 32 + 32;      // W col-off tap0 of cc+1
        const int xoffn = cc * 32 + 32;     // X cols of cc+1
        const bool more = (cc < 15);

        // tap0: read W0; stage W(t1) -> parity xb^1
        VMWAIT(0);
        issueW(xb ^ 1, kW1);
        compute_kt<0>(acc, W0, Xb, wm, wn, q, lr);

        // tap1: read W1; stage W(t2) -> parity xb; stage X(cc+1) -> parity xb^1
        VMWAIT(0);
        issueW(xb, kW2);
        if (more) issueX(xb ^ 1, xoffn);
        compute_kt<1>(acc, W1, Xb, wm, wn, q, lr);

        // tap2: read W0 (= W(t2)); stage W(t0,cc+1) -> parity xb^1
        if (more) { VMWAIT(3); } else { VMWAIT(0); }
        if (more) issueW(xb ^ 1, kW0n);
        compute_kt<2>(acc, W0, Xb, wm, wn, q, lr);
    }

    // ---- epilogue: D col = lane&15 = p, row = q*4 + reg = f ----
    const int fbase = m0 + wm * 64 + q * 4;
    const int pbase = n0 + wn * 64 + lr;
    if (mode == 0) {
        unsigned short* dst = (unsigned short*)j.dst;
#pragma unroll
        for (int i = 0; i < 4; ++i) {
            int f = fbase + i * 16;
            float4 bv = *(const float4*)(j.bias + f);
#pragma unroll
            for (int jj = 0; jj < 4; ++jj) {
                int p = pbase + jj * 16;
                ushort4 o;
                o.x = f2bf(fmaxf(acc[i][jj][0] + bv.x, 0.f));
                o.y = f2bf(fmaxf(acc[i][jj][1] + bv.y, 0.f));
                o.z = f2bf(fmaxf(acc[i][jj][2] + bv.z, 0.f));
                o.w = f2bf(fmaxf(acc[i][jj][3] + bv.w, 0.f));
                *(ushort4*)(dst + (long)p * C_ + f) = o;
            }
        }
    } else {
        float* dst = (float*)j.dst;
#pragma unroll
        for (int jj = 0; jj < 4; ++jj) {
            float s = 0.f;
#pragma unroll
            for (int i = 0; i < 4; ++i) {
                int f = fbase + i * 16;
                float4 bv = *(const float4*)(j.bias + f);
                float4 wv = *(const float4*)(j.wl + f);
                s += fmaxf(acc[i][jj][0] + bv.x, 0.f) * wv.x;
                s += fmaxf(acc[i][jj][1] + bv.y, 0.f) * wv.y;
                s += fmaxf(acc[i][jj][2] + bv.z, 0.f) * wv.z;
                s += fmaxf(acc[i][jj][3] + bv.w, 0.f) * wv.w;
            }
            s += __shfl_xor(s, 16, 64);
            s += __shfl_xor(s, 32, 64);
            if (l < 16) atomicAdd(dst + pbase + jj * 16, s);
        }
    }
}

// ---------------------------------------------------------------------------
extern "C" void kernel_launch(void* const* d_in, const int* in_sizes, int n_in,
                              void* d_out, int out_size, void* d_ws, size_t ws_size,
                              hipStream_t stream) {
    const float* H    = (const float*)d_in[0];
    const int*   Dgt  = (const int*)d_in[1];
    const float* Pgt  = (const float*)d_in[2];
    const float* Egt  = (const float*)d_in[3];
    const float* dp_w1 = (const float*)d_in[4];
    const float* dp_b1 = (const float*)d_in[5];
    const float* dp_w2 = (const float*)d_in[6];
    const float* dp_b2 = (const float*)d_in[7];
    const float* dp_wl = (const float*)d_in[8];
    const float* dp_bl = (const float*)d_in[9];
    const float* pp_w1 = (const float*)d_in[10];
    const float* pp_b1 = (const float*)d_in[11];
    const float* pp_w2 = (const float*)d_in[12];
    const float* pp_b2 = (const float*)d_in[13];
    const float* pp_wl = (const float*)d_in[14];
    const float* pp_bl = (const float*)d_in[15];
    const float* ep_w1 = (const float*)d_in[16];
    const float* ep_b1 = (const float*)d_in[17];
    const float* ep_w2 = (const float*)d_in[18];
    const float* ep_b2 = (const float*)d_in[19];
    const float* ep_wl = (const float*)d_in[20];
    const float* ep_bl = (const float*)d_in[21];
    const float* pitch_w  = (const float*)d_in[22];
    const float* pitch_b  = (const float*)d_in[23];
    const float* energy_w = (const float*)d_in[24];
    const float* energy_b = (const float*)d_in[25];

    float* out     = (float*)d_out;
    float* H_adapt = out;                       // 16*2048*512 = 16,777,216
    float* D_pred  = out + 16777216;            // 16*512 = 8192
    float* P_pred  = out + 16785408;            // 16*2048 = 32768
    float* E_pred  = out + 16818176;            // 16*2048 = 32768

    // ws_size is call-invariant, so this layout choice is graph-stable.
    const bool par = ws_size >= 94000000ull;    // parallel-ep plan needs ~89.1 MiB

    char* ws = (char*)d_ws;
    size_t off = 0;
    unsigned short* wpack = (unsigned short*)(ws + off); off += 6UL * 786432UL * 2UL;  // 9.4 MB
    unsigned short* Hbf   = (unsigned short*)(ws + off); off += 4194304UL * 2UL;       // 8 MB
    unsigned short* h1a   = (unsigned short*)(ws + off); off += 16777216UL * 2UL;      // 33.5 MB (pp)
    unsigned short* h1b   = par ? (unsigned short*)(ws + off) : h1a;                   // ep
    if (par) off += 16777216UL * 2UL;
    unsigned short* h1dp  = (unsigned short*)(ws + off); off += 4194304UL * 2UL;       // 8 MB
    unsigned short* zrow  = (unsigned short*)(ws + off); off += 512UL * 2UL;
    off = (off + 255) & ~(size_t)255;
    int* ridx_exp = (int*)(ws + off); off += (size_t)B_ * T_ * 4;

    hipLaunchKernelGGL(prep_kernel, dim3(10546), dim3(256), 0, stream,
                       dp_w1, dp_w2, pp_w1, pp_w2, ep_w1, ep_w2, wpack, H, Hbf, zrow,
                       Dgt, ridx_exp, D_pred, P_pred, E_pred, dp_bl, pp_bl, ep_bl);

    // nxshift = log2(position tiles at BN=128): pp 32768/128=256 -> 8; dp 8192/128=64 -> 6
    ConvJob j_pp1 = { Hbf,  ridx_exp, 11,  9, wpack + 2UL * 786432, pp_b1, nullptr, h1a,    8 };
    ConvJob j_ep1 = { Hbf,  ridx_exp, 11,  9, wpack + 4UL * 786432, ep_b1, nullptr, h1b,    8 };
    ConvJob j_dp1 = { Hbf,  nullptr,   9,  9, wpack + 0UL * 786432, dp_b1, nullptr, h1dp,   6 };
    ConvJob j_pp2 = { h1a,  nullptr,  11, 11, wpack + 3UL * 786432, pp_b2, pp_wl,  P_pred, 8 };
    ConvJob j_ep2 = { h1b,  nullptr,  11, 11, wpack + 5UL * 786432, ep_b2, ep_wl,  E_pred, 8 };
    ConvJob j_dp2 = { h1dp, nullptr,   9,  9, wpack + 1UL * 786432, dp_b2, dp_wl,  D_pred, 6 };

    const unsigned lds_bytes = 33024;   // W 2x8192B + X 2x8320B

    if (par) {
        // conv1 all three (1024+1024+256=2304) + half of adapt (1024)
        hipLaunchKernelGGL(mega_kernel, dim3(2304 + 1024), dim3(256), lds_bytes, stream,
                           j_pp1, j_ep1, j_dp1, 1024, 2048, 2304, 0, 0, zrow,
                           H, ridx_exp, Pgt, Egt, pitch_w, pitch_b, energy_w, energy_b, H_adapt);
        // conv2 + fused final linear + second half of adapt
        hipLaunchKernelGGL(mega_kernel, dim3(2304 + 1024), dim3(256), lds_bytes, stream,
                           j_pp2, j_ep2, j_dp2, 1024, 2048, 2304, 1, 1024, zrow,
                           H, ridx_exp, Pgt, Egt, pitch_w, pitch_b, energy_w, energy_b, H_adapt);
    } else {
        // serialized ep (h1b aliases h1a): pp+dp first (+all adapt), then ep
        hipLaunchKernelGGL(mega_kernel, dim3(1280 + 2048), dim3(256), lds_bytes, stream,
                           j_pp1, j_dp1, j_dp1, 1024, 1280, 1280, 0, 0, zrow,
                           H, ridx_exp, Pgt, Egt, pitch_w, pitch_b, energy_w, energy_b, H_adapt);
        hipLaunchKernelGGL(mega_kernel, dim3(1280), dim3(256), lds_bytes, stream,
                           j_pp2, j_dp2, j_dp2, 1024, 1280, 1280, 1, 0, zrow,
                           H, ridx_exp, Pgt, Egt, pitch_w, pitch_b, energy_w, energy_b, H_adapt);
        hipLaunchKernelGGL(mega_kernel, dim3(1024), dim3(256), lds_bytes, stream,
                           j_ep1, j_ep1, j_ep1, 1024, 1024, 1024, 0, 0, zrow,
                           H, ridx_exp, Pgt, Egt, pitch_w, pitch_b, energy_w, energy_b, H_adapt);
        hipLaunchKernelGGL(mega_kernel, dim3(1024), dim3(256), lds_bytes, stream,
                           j_ep2, j_ep2, j_ep2, 1024, 1024, 1024, 1, 0, zrow,
                           H, ridx_exp, Pgt, Egt, pitch_w, pitch_b, energy_w, energy_b, H_adapt);
    }
}

// Round 7
// 344.611 us; speedup vs baseline: 1.4947x; 1.0241x over previous
//
#include <hip/hip_runtime.h>

// VarianceAdaptor: B=16, S=512, C(D_MODEL)=F(FILTER)=512, K=3, T(MAX_FRAMES)=2048
#define B_ 16
#define S_ 512
#define C_ 512
#define T_ 2048

typedef __attribute__((ext_vector_type(8))) short short8;
typedef __attribute__((ext_vector_type(4))) float floatx4;

__device__ __forceinline__ unsigned short f2bf(float x) {
    union { float f; unsigned u; } c; c.f = x;
    unsigned r = (c.u + 0x7fffu + ((c.u >> 16) & 1u)) >> 16;
    return (unsigned short)r;
}

// async global->LDS, 16B per lane; lds dest = wave-uniform base + lane*16
__device__ __forceinline__ void gld_lds16(void* l, const void* g) {
    __builtin_amdgcn_global_load_lds(
        (const __attribute__((address_space(1))) void*)g,
        (__attribute__((address_space(3))) void*)l, 16, 0, 0);
}

// ---------------------------------------------------------------------------
// Fused prep (unchanged): pack 6 conv weights (F,C,3)fp32 -> (3,F,C)bf16,
// cast H->bf16, zero zrow, length-regulator rowidx, fill preds w/ final bias.
__global__ void prep_kernel(const float* __restrict__ w0, const float* __restrict__ w1,
                            const float* __restrict__ w2, const float* __restrict__ w3,
                            const float* __restrict__ w4, const float* __restrict__ w5,
                            unsigned short* __restrict__ wpack,
                            const float* __restrict__ H, unsigned short* __restrict__ Hbf,
                            unsigned short* __restrict__ zrow,
                            const int* __restrict__ Dgt, int* __restrict__ ridx,
                            float* __restrict__ Dp, float* __restrict__ Pp, float* __restrict__ Ep,
                            const float* __restrict__ dbl, const float* __restrict__ pbl,
                            const float* __restrict__ ebl) {
    __shared__ int cs[S_];
    __shared__ int ps[256];
    int blk = blockIdx.x;
    int tid = threadIdx.x;
    if (blk < 6144) {                      // weight pack: 6 x 1024 blocks
        int which = blk >> 10;
        const float* w = which == 0 ? w0 : which == 1 ? w1 : which == 2 ? w2
                       : which == 3 ? w3 : which == 4 ? w4 : w5;
        unsigned short* wp = wpack + (long)which * 786432;
        int i = (blk & 1023) * 256 + tid;   // i over F*C = 262144
        const float* s = w + (long)i * 3;
        wp[i]          = f2bf(s[0]);
        wp[i + 262144] = f2bf(s[1]);
        wp[i + 524288] = f2bf(s[2]);
    } else if (blk < 10240) {              // H fp32 -> bf16: 4096 blocks x 4 elems
        int i = (blk - 6144) * 256 + tid;
        float4 v = *(const float4*)(H + (long)i * 4);
        ushort4 o;
        o.x = f2bf(v.x); o.y = f2bf(v.y); o.z = f2bf(v.z); o.w = f2bf(v.w);
        *(ushort4*)(Hbf + (long)i * 4) = o;
    } else if (blk < 10242) {              // zrow: 2 blocks
        zrow[(blk - 10240) * 256 + tid] = 0;
    } else if (blk < 10258) {              // expand rowidx: 16 blocks (one/batch)
        int b = blk - 10242;
        int t2 = tid * 2;
        int d0 = Dgt[b * S_ + t2], d1 = Dgt[b * S_ + t2 + 1];
        int a0 = d0 < 0 ? 0 : d0, a1 = d1 < 0 ? 0 : d1;
        ps[tid] = a0 + a1;
        __syncthreads();
        for (int off = 1; off < 256; off <<= 1) {
            int v = (tid >= off) ? ps[tid - off] : 0;
            __syncthreads();
            ps[tid] += v;
            __syncthreads();
        }
        int incl = ps[tid];
        cs[t2] = incl - a1;
        cs[t2 + 1] = incl;
        __syncthreads();
        int total = cs[S_ - 1];
        int limit = total < T_ ? total : T_;
        for (int t = tid; t < T_; t += 256) {
            int lo = 0, hi = S_;
            while (lo < hi) { int mid = (lo + hi) >> 1; if (cs[mid] <= t) lo = mid + 1; else hi = mid; }
            if (lo > S_ - 1) lo = S_ - 1;
            ridx[b * T_ + t] = (t < limit) ? lo : -1;
        }
    } else {                               // fill preds: 288 blocks
        int i = (blk - 10258) * 256 + tid;
        if (i < 8192) Dp[i] = dbl[0];
        else if (i < 40960) Pp[i - 8192] = pbl[0];
        else Ep[i - 40960] = ebl[0];
    }
}

// ---------------------------------------------------------------------------
// 128(f) x 256(p) tile, 4 waves (2x2), wave = 64x128, acc[4][8].  BK=32,
// tap-minor counted-vmcnt pipeline (R6-verified sync skeleton).
//   D[f, p] = sum_{tap, c} W[tap][f][c] * X[row(p + tap - 1)][c]
// Rationale: R2/R6 both hit 43.5% MfmaUtil = the 64x64-wave-tile LDS-BW
// ceiling (reads+staging-writes ~512KB per c-block cohort = 2000cy vs MFMA
// 932cy -> 46.6%).  64x128 wave raises FLOP/LDS-byte 32 -> 42.7 and halves
// W-stage bytes per FLOP -> ceiling ~65%.  Cost: ~190 VGPR -> 2 blocks/CU.
// K-tiles: c-block-major (cc=0..15), tap-minor.  X staged once per cc
// (parity cc&1, 5 instrs incl. edge rows 256/257); W per kt (2 instrs,
// parity (cc+tap)&1).  Waits: tap0/tap1 vmcnt(0) (>=1 kt slack),
// tap2 vmcnt(5) keeps the 5 X-loads of cc+1 in flight.
// Swizzle: rows of 32 shorts (4 x 16B chunks); chunk c8 of row r holds
// global chunk c8 ^ ((r>>1)&3); linear LDS dest, inverse-swizzled source.
struct ConvJob {
    const unsigned short* X;    // bf16 rows [B << Bshift][C]
    const int* ridx;            // per (b,t) row-in-batch, or nullptr = identity
    int Lshift;                 // log2 positions per batch
    int Bshift;                 // log2 rows per batch of X
    const unsigned short* wp;   // [3][512][512] bf16
    const float* bias;
    const float* wl;
    void* dst;
    int nxshift;                // log2 of position tiles (BN=256)
};

template <int TAP>
__device__ __forceinline__ void compute_kt(
    floatx4 (&acc)[4][8],
    const unsigned short* Wb, const unsigned short* Xb,
    int wm, int wn, int q, int lr)
{
    // B (X) frags: row wn*128 + jj*16 + lr + TAP; stored chunk q^((row>>1)&3)
    short8 bfr[8];
    const int sX = ((lr + TAP) >> 1) & 3;
#pragma unroll
    for (int jj = 0; jj < 8; ++jj) {
        const int xr = wn * 128 + jj * 16 + lr + TAP;
        bfr[jj] = *(const short8*)(Xb + xr * 32 + ((q ^ sX) * 8));
    }
    const int sA = (lr >> 1) & 3;
#pragma unroll
    for (int i = 0; i < 4; ++i) {
        const int rA = wm * 64 + i * 16 + lr;
        short8 a = *(const short8*)(Wb + rA * 32 + ((q ^ sA) * 8));
#pragma unroll
        for (int jj = 0; jj < 8; ++jj)
            acc[i][jj] = __builtin_amdgcn_mfma_f32_16x16x32_bf16(a, bfr[jj], acc[i][jj], 0, 0, 0);
    }
}

// counted wait + publish barrier at K-tile start
#define VMWAIT(n) do { \
    asm volatile("s_waitcnt vmcnt(" #n ")" ::: "memory"); \
    __builtin_amdgcn_sched_barrier(0); \
    __builtin_amdgcn_s_barrier(); \
    __builtin_amdgcn_sched_barrier(0); \
} while (0)

__global__ __launch_bounds__(256, 2) void mega_kernel(
    ConvJob j0, ConvJob j1, ConvJob j2, int e0, int e1, int e2, int mode, int aoff,
    const unsigned short* __restrict__ zrow,
    const float* __restrict__ H, const int* __restrict__ aridx,
    const float* __restrict__ Pgt, const float* __restrict__ Egt,
    const float* __restrict__ pw, const float* __restrict__ pb,
    const float* __restrict__ ew, const float* __restrict__ eb,
    float* __restrict__ aout)
{
    extern __shared__ unsigned short lds[];   // 49408 B: W[2][4096] + X[2][8256] shorts
    const int bx = blockIdx.x;
    const int tid = threadIdx.x;

    if (bx >= e2) {
        // ---- adapt path: aoff selects which part of the 2048-block range ----
        int ab = bx - e2 + aoff;
#pragma unroll
        for (int it = 0; it < 8; ++it) {
            int i = ab * 256 + tid + it * 524288;
            int f4 = i & 127;
            int p  = i >> 7;
            int b  = p >> 11;
            int r  = aridx[p];
            float pg = Pgt[p], eg = Egt[p];
            int f = f4 << 2;
            float4 pwv = *(const float4*)(pw + f);
            float4 pbv = *(const float4*)(pb + f);
            float4 ewv = *(const float4*)(ew + f);
            float4 ebv = *(const float4*)(eb + f);
            float4 h = make_float4(0.f, 0.f, 0.f, 0.f);
            if (r >= 0) h = *(const float4*)(H + ((long)b * S_ + r) * C_ + f);
            float4 o;
            o.x = h.x + pg * pwv.x + pbv.x + eg * ewv.x + ebv.x;
            o.y = h.y + pg * pwv.y + pbv.y + eg * ewv.y + ebv.y;
            o.z = h.z + pg * pwv.z + pbv.z + eg * ewv.z + ebv.z;
            o.w = h.w + pg * pwv.w + pbv.w + eg * ewv.w + ebv.w;
            *(float4*)(aout + (long)p * C_ + f) = o;
        }
        return;
    }

    ConvJob j;
    int local;
    if (bx < e0)      { j = j0; local = bx; }
    else if (bx < e1) { j = j1; local = bx - e0; }
    else              { j = j2; local = bx - e1; }
    const int m0 = (local >> j.nxshift) * 128;              // f tile (BM=128)
    const int n0 = (local & ((1 << j.nxshift) - 1)) * 256;  // p tile (BN=256)
    const int L = 1 << j.Lshift;
    const int b = n0 >> j.Lshift;
    const int t0 = n0 & (L - 1);

    unsigned short* WtS = lds;            // [2][4096]  (128 rows x 32) x 2
    unsigned short* XtS = lds + 8192;     // [2][8256]  (258 rows x 32) x 2
    char* WtB = (char*)WtS;
    char* XtB = (char*)XtS;

    const int w = tid >> 6, l = tid & 63;
    const int q = l >> 4, lr = l & 15;
    const int wm = w & 1, wn = w >> 1;

    floatx4 acc[4][8];
#pragma unroll
    for (int i = 0; i < 4; ++i)
#pragma unroll
        for (int jj = 0; jj < 8; ++jj) acc[i][jj] = (floatx4){0.f, 0.f, 0.f, 0.f};

    // ---- staging sources (16B chunks; inverse-swizzled source column) ----
    // issue qq stages chunk ch = qq*256 + tid: row = qq*64 + (tid>>2), c8 = tid&3;
    // source col-chunk = c8 ^ ((row>>1)&3) = (tid&3) ^ ((tid>>3)&3).
    const int sw = (((tid & 3) ^ ((tid >> 3) & 3))) * 8;
    auto xrowp = [&](int r) -> const unsigned short* {
        int t = t0 - 1 + r;
        if (t < 0 || t >= L) return zrow;
        int rr = j.ridx ? j.ridx[(b << j.Lshift) + t] : t;
        if (rr < 0) return zrow;
        return j.X + ((long)(b << j.Bshift) + rr) * C_;
    };
    const unsigned short* wsrc[2];
    const unsigned short* xsrc[4];
#pragma unroll
    for (int qq = 0; qq < 2; ++qq)
        wsrc[qq] = j.wp + (long)(m0 + qq * 64 + (tid >> 2)) * C_ + sw;
#pragma unroll
    for (int qq = 0; qq < 4; ++qq)
        xsrc[qq] = xrowp(qq * 64 + (tid >> 2)) + sw;
    // extra X rows 256,257: chunks ch_e = w*2 + (l&1); (row_e>>1)&3 == 0
    const int ch_e = w * 2 + (l & 1);
    const unsigned short* xsrcE = xrowp(256 + (ch_e >> 2)) + (ch_e & 3) * 8;

    auto issueW = [&](int buf, int koff) {             // 2 instrs, 8 KB
        gld_lds16(WtB + buf * 8192 + 0 * 4096 + w * 1024, wsrc[0] + koff);
        gld_lds16(WtB + buf * 8192 + 1 * 4096 + w * 1024, wsrc[1] + koff);
    };
    auto issueX = [&](int buf, int xoff) {             // 5 instrs, 16.5 KB
        gld_lds16(XtB + buf * 16512 + 0 * 4096 + w * 1024, xsrc[0] + xoff);
        gld_lds16(XtB + buf * 16512 + 1 * 4096 + w * 1024, xsrc[1] + xoff);
        gld_lds16(XtB + buf * 16512 + 2 * 4096 + w * 1024, xsrc[2] + xoff);
        gld_lds16(XtB + buf * 16512 + 3 * 4096 + w * 1024, xsrc[3] + xoff);
        if (l < 2)
            gld_lds16(XtB + buf * 16512 + 16384 + w * 32, xsrcE + xoff);
    };

    // ---- prologue: X(cc=0) [5 ops] + W(cc0,tap0) [2 ops] ----
    issueX(0, 0);
    issueW(0, 0);

    // ---- main loop.  W parity of kt (cc,tap) = (cc+tap)&1; X parity = cc&1.
    // Waits at kt start (outstanding per wave -> count):
    //  tap0: X(cc)[5] + W(t0)[2], all >= 1 kt old      -> vmcnt(0)
    //  tap1: W(t1)[2], 1 kt old                        -> vmcnt(0)
    //  tap2: W(t2)[2, 1kt old] + X(cc+1)[5, just sent] -> vmcnt(5) keep X flying
#pragma unroll 1
    for (int cc = 0; cc < 16; ++cc) {
        const int xb = cc & 1;
        const unsigned short* Xb = XtS + xb * 8256;
        const unsigned short* W0 = WtS + xb * 4096;          // parity cc&1 (tap0, tap2)
        const unsigned short* W1 = WtS + (xb ^ 1) * 4096;    // parity (cc+1)&1 (tap1)
        const int kW1 = 262144 + cc * 32;   // W col-off tap1
        const int kW2 = 524288 + cc * 32;   // W col-off tap2
        const int kW0n = cc * 32 + 32;      // W col-off tap0 of cc+1
        const int xoffn = cc * 32 + 32;     // X cols of cc+1
        const bool more = (cc < 15);

        // tap0: read W0; stage W(t1) -> parity xb^1
        VMWAIT(0);
        issueW(xb ^ 1, kW1);
        compute_kt<0>(acc, W0, Xb, wm, wn, q, lr);

        // tap1: read W1; stage W(t2) -> parity xb; stage X(cc+1) -> parity xb^1
        VMWAIT(0);
        issueW(xb, kW2);
        if (more) issueX(xb ^ 1, xoffn);
        compute_kt<1>(acc, W1, Xb, wm, wn, q, lr);

        // tap2: read W0 (= W(t2)); stage W(t0,cc+1) -> parity xb^1
        if (more) { VMWAIT(5); } else { VMWAIT(0); }
        if (more) issueW(xb ^ 1, kW0n);
        compute_kt<2>(acc, W0, Xb, wm, wn, q, lr);
    }

    // ---- epilogue: D col = lane&15 = p, row = q*4 + reg = f ----
    const int fbase = m0 + wm * 64 + q * 4;
    const int pbase = n0 + wn * 128 + lr;
    if (mode == 0) {
        unsigned short* dst = (unsigned short*)j.dst;
#pragma unroll
        for (int i = 0; i < 4; ++i) {
            int f = fbase + i * 16;
            float4 bv = *(const float4*)(j.bias + f);
#pragma unroll
            for (int jj = 0; jj < 8; ++jj) {
                int p = pbase + jj * 16;
                ushort4 o;
                o.x = f2bf(fmaxf(acc[i][jj][0] + bv.x, 0.f));
                o.y = f2bf(fmaxf(acc[i][jj][1] + bv.y, 0.f));
                o.z = f2bf(fmaxf(acc[i][jj][2] + bv.z, 0.f));
                o.w = f2bf(fmaxf(acc[i][jj][3] + bv.w, 0.f));
                *(ushort4*)(dst + (long)p * C_ + f) = o;
            }
        }
    } else {
        float* dst = (float*)j.dst;
#pragma unroll
        for (int jj = 0; jj < 8; ++jj) {
            float s = 0.f;
#pragma unroll
            for (int i = 0; i < 4; ++i) {
                int f = fbase + i * 16;
                float4 bv = *(const float4*)(j.bias + f);
                float4 wv = *(const float4*)(j.wl + f);
                s += fmaxf(acc[i][jj][0] + bv.x, 0.f) * wv.x;
                s += fmaxf(acc[i][jj][1] + bv.y, 0.f) * wv.y;
                s += fmaxf(acc[i][jj][2] + bv.z, 0.f) * wv.z;
                s += fmaxf(acc[i][jj][3] + bv.w, 0.f) * wv.w;
            }
            s += __shfl_xor(s, 16, 64);
            s += __shfl_xor(s, 32, 64);
            if (l < 16) atomicAdd(dst + pbase + jj * 16, s);
        }
    }
}

// ---------------------------------------------------------------------------
extern "C" void kernel_launch(void* const* d_in, const int* in_sizes, int n_in,
                              void* d_out, int out_size, void* d_ws, size_t ws_size,
                              hipStream_t stream) {
    const float* H    = (const float*)d_in[0];
    const int*   Dgt  = (const int*)d_in[1];
    const float* Pgt  = (const float*)d_in[2];
    const float* Egt  = (const float*)d_in[3];
    const float* dp_w1 = (const float*)d_in[4];
    const float* dp_b1 = (const float*)d_in[5];
    const float* dp_w2 = (const float*)d_in[6];
    const float* dp_b2 = (const float*)d_in[7];
    const float* dp_wl = (const float*)d_in[8];
    const float* dp_bl = (const float*)d_in[9];
    const float* pp_w1 = (const float*)d_in[10];
    const float* pp_b1 = (const float*)d_in[11];
    const float* pp_w2 = (const float*)d_in[12];
    const float* pp_b2 = (const float*)d_in[13];
    const float* pp_wl = (const float*)d_in[14];
    const float* pp_bl = (const float*)d_in[15];
    const float* ep_w1 = (const float*)d_in[16];
    const float* ep_b1 = (const float*)d_in[17];
    const float* ep_w2 = (const float*)d_in[18];
    const float* ep_b2 = (const float*)d_in[19];
    const float* ep_wl = (const float*)d_in[20];
    const float* ep_bl = (const float*)d_in[21];
    const float* pitch_w  = (const float*)d_in[22];
    const float* pitch_b  = (const float*)d_in[23];
    const float* energy_w = (const float*)d_in[24];
    const float* energy_b = (const float*)d_in[25];

    float* out     = (float*)d_out;
    float* H_adapt = out;                       // 16*2048*512 = 16,777,216
    float* D_pred  = out + 16777216;            // 16*512 = 8192
    float* P_pred  = out + 16785408;            // 16*2048 = 32768
    float* E_pred  = out + 16818176;            // 16*2048 = 32768

    // ws_size is call-invariant, so this layout choice is graph-stable.
    const bool par = ws_size >= 94000000ull;    // parallel-ep plan needs ~89.1 MiB

    char* ws = (char*)d_ws;
    size_t off = 0;
    unsigned short* wpack = (unsigned short*)(ws + off); off += 6UL * 786432UL * 2UL;  // 9.4 MB
    unsigned short* Hbf   = (unsigned short*)(ws + off); off += 4194304UL * 2UL;       // 8 MB
    unsigned short* h1a   = (unsigned short*)(ws + off); off += 16777216UL * 2UL;      // 33.5 MB (pp)
    unsigned short* h1b   = par ? (unsigned short*)(ws + off) : h1a;                   // ep
    if (par) off += 16777216UL * 2UL;
    unsigned short* h1dp  = (unsigned short*)(ws + off); off += 4194304UL * 2UL;       // 8 MB
    unsigned short* zrow  = (unsigned short*)(ws + off); off += 512UL * 2UL;
    off = (off + 255) & ~(size_t)255;
    int* ridx_exp = (int*)(ws + off); off += (size_t)B_ * T_ * 4;

    hipLaunchKernelGGL(prep_kernel, dim3(10546), dim3(256), 0, stream,
                       dp_w1, dp_w2, pp_w1, pp_w2, ep_w1, ep_w2, wpack, H, Hbf, zrow,
                       Dgt, ridx_exp, D_pred, P_pred, E_pred, dp_bl, pp_bl, ep_bl);

    // nxshift = log2(position tiles at BN=256): pp 32768/256=128 -> 7; dp 8192/256=32 -> 5
    // grids: pp = 4(f) x 128 = 512 blocks; dp = 4 x 32 = 128 blocks
    ConvJob j_pp1 = { Hbf,  ridx_exp, 11,  9, wpack + 2UL * 786432, pp_b1, nullptr, h1a,    7 };
    ConvJob j_ep1 = { Hbf,  ridx_exp, 11,  9, wpack + 4UL * 786432, ep_b1, nullptr, h1b,    7 };
    ConvJob j_dp1 = { Hbf,  nullptr,   9,  9, wpack + 0UL * 786432, dp_b1, nullptr, h1dp,   5 };
    ConvJob j_pp2 = { h1a,  nullptr,  11, 11, wpack + 3UL * 786432, pp_b2, pp_wl,  P_pred, 7 };
    ConvJob j_ep2 = { h1b,  nullptr,  11, 11, wpack + 5UL * 786432, ep_b2, ep_wl,  E_pred, 7 };
    ConvJob j_dp2 = { h1dp, nullptr,   9,  9, wpack + 1UL * 786432, dp_b2, dp_wl,  D_pred, 5 };

    const unsigned lds_bytes = 49408;   // W 2x8192B + X 2x16512B

    if (par) {
        // conv1 all three (512+512+128=1152) + half of adapt (1024)
        hipLaunchKernelGGL(mega_kernel, dim3(1152 + 1024), dim3(256), lds_bytes, stream,
                           j_pp1, j_ep1, j_dp1, 512, 1024, 1152, 0, 0, zrow,
                           H, ridx_exp, Pgt, Egt, pitch_w, pitch_b, energy_w, energy_b, H_adapt);
        // conv2 + fused final linear + second half of adapt
        hipLaunchKernelGGL(mega_kernel, dim3(1152 + 1024), dim3(256), lds_bytes, stream,
                           j_pp2, j_ep2, j_dp2, 512, 1024, 1152, 1, 1024, zrow,
                           H, ridx_exp, Pgt, Egt, pitch_w, pitch_b, energy_w, energy_b, H_adapt);
    } else {
        // serialized ep (h1b aliases h1a): pp+dp first (+all adapt), then ep
        hipLaunchKernelGGL(mega_kernel, dim3(640 + 2048), dim3(256), lds_bytes, stream,
                           j_pp1, j_dp1, j_dp1, 512, 640, 640, 0, 0, zrow,
                           H, ridx_exp, Pgt, Egt, pitch_w, pitch_b, energy_w, energy_b, H_adapt);
        hipLaunchKernelGGL(mega_kernel, dim3(640), dim3(256), lds_bytes, stream,
                           j_pp2, j_dp2, j_dp2, 512, 640, 640, 1, 0, zrow,
                           H, ridx_exp, Pgt, Egt, pitch_w, pitch_b, energy_w, energy_b, H_adapt);
        hipLaunchKernelGGL(mega_kernel, dim3(512), dim3(256), lds_bytes, stream,
                           j_ep1, j_ep1, j_ep1, 512, 512, 512, 0, 0, zrow,
                           H, ridx_exp, Pgt, Egt, pitch_w, pitch_b, energy_w, energy_b, H_adapt);
        hipLaunchKernelGGL(mega_kernel, dim3(512), dim3(256), lds_bytes, stream,
                           j_ep2, j_ep2, j_ep2, 512, 512, 512, 1, 0, zrow,
                           H, ridx_exp, Pgt, Egt, pitch_w, pitch_b, energy_w, energy_b, H_adapt);
    }
}